// Round 10
// baseline (130.738 us; speedup 1.0000x reference)
//
#include <hip/hip_runtime.h>
#include <math.h>

// R10 theory: R9's LDS-sampling idea was right (LDS pipe + conflicts were
// cheap); its PACKAGING was wrong (block-per-point doubled VALU: 256-thread
// redundant setup, idle ring waves, 2 barriers, fixed 64x64 staging).
// R10 repackages wave-grained: one 64-thread block per point, wave-private
// 58x64 tile (15.8 KB, ~10 blocks/CU), rows sized to the actual bbox
// (avg ~40), staged with coalesced float4 loads. Then the EXACT R8
// 16-iteration loop with taps from LDS (ds_read2_b32 pairs) -- divergent
// gathers leave the saturated TA path (R8: ~52cy/gather, occupancy-
// insensitive) for the idle LDS pipe. Oversized ellipses (Ri|Rj > 28 px,
// ~8%) keep the proven R8 gather path (wave-uniform branch). Accumulation
// order identical to R8 -> identical absmax.

constexpr int TROWS = 58;   // max rows: 2*28+2
constexpr int TS    = 68;   // row stride (floats): bank=(4r+c)%32, ~2-way

__global__ __launch_bounds__(64) void contrast_kernel_wtile(
    const float* __restrict__ points,   // (S*P, 5)
    const float* __restrict__ mask,     // (S*P)
    const float* __restrict__ img,      // (2048, 2048)
    float* __restrict__ out,            // (S*P)
    int n_points)
{
    __shared__ float tile[TROWS * TS];  // 15776 B, wave-private (1 wave/block)

    const int pid  = (int)blockIdx.x;
    const int lane = (int)(threadIdx.x & 63u);
    if (pid >= n_points) return;

    const float* pt = points + (size_t)pid * 5;
    const float px = pt[0];
    const float py = pt[1];
    const float a  = pt[2];
    const float b  = pt[3];
    const float th = pt[4];

    float sn, cs;
    sincosf(th, &sn, &cs);
    const float A00 = a * cs, A01 = -b * sn;   // i (row)
    const float A10 = a * sn, A11 =  b * cs;   // j (col)

    // bbox half-extents over the full stencil square [-1.0625, 1.0625]^2
    const float Ri = (fabsf(A00) + fabsf(A01)) * 1.0625f;
    const float Rj = (fabsf(A10) + fabsf(A11)) * 1.0625f;
    const bool use_lds = (Ri <= 28.f) && (Rj <= 28.f);   // rows<=58, cols<=62 covered

    int r0 = 0, c0 = 0;
    if (use_lds) {
        const int rlo = (int)floorf(px - Ri);
        const int clo = (int)floorf(py - Rj);
        r0 = min(max(rlo, 0), 2048 - TROWS);      // stage rows r0..r0+rows-1 (<=2047)
        c0 = min(max(clo & ~3, 0), 2048 - 64);    // 16B-aligned col origin, 64 cols
        const int rhi  = min((int)floorf(px + Ri), 2046);
        const int rows = min(max(rhi - r0 + 2, 1), TROWS);  // includes bilinear +1 row
        const int rr = lane >> 4;                 // 0..3   (4 rows per iteration)
        const int cc = (lane & 15) << 2;          // 0..60  (16 quads per row)
        for (int base = 0; base < rows; base += 4) {
            const int rl = base + rr;
            if (rl < rows) {
                const float4 v = *reinterpret_cast<const float4*>(
                    &img[((unsigned)(r0 + rl) << 11) + (unsigned)(c0 + cc)]);
                *reinterpret_cast<float4*>(&tile[rl * TS + cc]) = v;
            }
        }
        // no barrier needed: tile is wave-private; compiler orders via lgkmcnt
    }

    // ---- interior: exact R8 loop, taps from LDS (or gather fallback) ----
    const int   lr = lane >> 3;
    const int   lc = lane & 7;
    const float syb = fmaf((float)lr, 0.0625f, 0.03125f) - 1.0f;
    const float sxb = fmaf((float)lc, 0.0625f, 0.03125f) - 1.0f;

    float s0 = 0.f, q0 = 0.f, s1 = 0.f, q1 = 0.f;
    #pragma unroll 4
    for (int it = 0; it < 16; ++it) {
        const float dr = (float)(it >> 2) * 0.5f;   // exact
        const float dc = (float)(it & 3) * 0.5f;
        const float sy = syb + dr;
        const float sx = sxb + dc;
        const float ci = fmaf(A00, sy, fmaf(A01, sx, px));
        const float cj = fmaf(A10, sy, fmaf(A11, sx, py));
        const float fi = fminf(fmaxf(floorf(ci), 0.f), 2046.f);
        const float fj = fminf(fmaxf(floorf(cj), 0.f), 2046.f);
        const float di = fminf(fmaxf(ci - fi, 0.f), 1.f);
        const float dj = fminf(fmaxf(cj - fj, 0.f), 1.f);
        float v00, v01, v10, v11;
        if (use_lds) {
            const int o = ((int)fi - r0) * TS + ((int)fj - c0);
            v00 = tile[o];      v01 = tile[o + 1];
            v10 = tile[o + TS]; v11 = tile[o + TS + 1];
        } else {
            const unsigned idx = ((unsigned)(int)fi << 11) + (unsigned)(int)fj;
            float2 t0, t1;
            __builtin_memcpy(&t0, &img[idx],         sizeof(float2));
            __builtin_memcpy(&t1, &img[idx + 2048u], sizeof(float2));
            v00 = t0.x; v01 = t0.y; v10 = t1.x; v11 = t1.y;
        }
        const float top = fmaf(v01 - v00, dj, v00);
        const float bot = fmaf(v11 - v10, dj, v10);
        const float v   = fmaf(bot - top, di, top);
        if (it & 1) { s1 += v; q1 = fmaf(v, v, q1); }
        else        { s0 += v; q0 = fmaf(v, v, q0); }
    }
    float sum_in = s0 + s1;
    float sq_in  = q0 + q1;

    // ---- ring: 124 samples, 2 iterations (same wave) ----
    float sum_out = 0.f, sq_out = 0.f;
    #pragma unroll
    for (int base = 0; base < 124; base += 64) {
        const int n = base + lane;
        if (n < 124) {
            int row, col;
            if (n < 32)      { row = 0;                   col = n; }
            else if (n < 92) { row = 1 + ((n - 32) >> 1); col = (n & 1) * 31; }
            else             { row = 31;                  col = n - 92; }
            const float sy  = (fmaf((float)row, 0.0625f, 0.03125f) - 1.0f) * 1.0625f;
            const float sxo = (fmaf((float)col, 0.0625f, 0.03125f) - 1.0f) * 1.0625f;
            const float ci = fmaf(A00, sy, fmaf(A01, sxo, px));
            const float cj = fmaf(A10, sy, fmaf(A11, sxo, py));
            const float fi = fminf(fmaxf(floorf(ci), 0.f), 2046.f);
            const float fj = fminf(fmaxf(floorf(cj), 0.f), 2046.f);
            const float di = fminf(fmaxf(ci - fi, 0.f), 1.f);
            const float dj = fminf(fmaxf(cj - fj, 0.f), 1.f);
            float v00, v01, v10, v11;
            if (use_lds) {
                const int o = ((int)fi - r0) * TS + ((int)fj - c0);
                v00 = tile[o];      v01 = tile[o + 1];
                v10 = tile[o + TS]; v11 = tile[o + TS + 1];
            } else {
                const unsigned idx = ((unsigned)(int)fi << 11) + (unsigned)(int)fj;
                float2 t0, t1;
                __builtin_memcpy(&t0, &img[idx],         sizeof(float2));
                __builtin_memcpy(&t1, &img[idx + 2048u], sizeof(float2));
                v00 = t0.x; v01 = t0.y; v10 = t1.x; v11 = t1.y;
            }
            const float top = fmaf(v01 - v00, dj, v00);
            const float bot = fmaf(v11 - v10, dj, v10);
            const float v   = fmaf(bot - top, di, top);
            sum_out += v;
            sq_out = fmaf(v, v, sq_out);
        }
    }

    #pragma unroll
    for (int off = 32; off > 0; off >>= 1) {
        sum_in  += __shfl_xor(sum_in,  off);
        sq_in   += __shfl_xor(sq_in,   off);
        sum_out += __shfl_xor(sum_out, off);
        sq_out  += __shfl_xor(sq_out,  off);
    }

    if (lane == 0) {
        const float ni = 1024.f, no = 124.f;
        const float m_in  = sum_in  / ni;
        const float m_out = sum_out / no;
        const float v_in  = (sq_in  - ni * m_in  * m_in ) / (ni - 1.f);
        const float v_out = (sq_out - no * m_out * m_out) / (no - 1.f);
        const float contrast = (m_in - m_out) / sqrtf(v_in + v_out + 1e-8f);
        out[pid] = contrast * mask[pid];
    }
}

// ---------------- generic fallback for other sizes ----------------
__global__ __launch_bounds__(256) void contrast_kernel_generic(
    const float* __restrict__ points, const float* __restrict__ mask,
    const float* __restrict__ img, const float* __restrict__ st_in,
    const float* __restrict__ st_out, float* __restrict__ out,
    int n_points, int n_in, int n_out, int Himg, int Wimg)
{
    const int wave = (int)((blockIdx.x * (unsigned)blockDim.x + threadIdx.x) >> 6);
    const int lane = (int)(threadIdx.x & 63u);
    if (wave >= n_points) return;
    const float* pt = points + (size_t)wave * 5;
    const float px = pt[0], py = pt[1], a = pt[2], b = pt[3], th = pt[4];
    float sn, cs; sincosf(th, &sn, &cs);
    const float A00 = a * cs, A01 = -b * sn, A10 = a * sn, A11 = b * cs;
    const float fImax = (float)(Himg - 2), fJmax = (float)(Wimg - 2);
    float sum_in = 0.f, sq_in = 0.f;
    for (int base = 0; base < n_in; base += 64) {
        const int n = base + lane;
        if (n < n_in) {
            const float sy = st_in[n * 3 + 0], sx = st_in[n * 3 + 1];
            const float ci = fmaf(A00, sy, fmaf(A01, sx, px));
            const float cj = fmaf(A10, sy, fmaf(A11, sx, py));
            const float fi = fminf(fmaxf(floorf(ci), 0.f), fImax);
            const float fj = fminf(fmaxf(floorf(cj), 0.f), fJmax);
            const float di = fminf(fmaxf(ci - fi, 0.f), 1.f);
            const float dj = fminf(fmaxf(cj - fj, 0.f), 1.f);
            const float* p0 = img + ((int)fi * Wimg + (int)fj);
            const float v00 = p0[0], v01 = p0[1], v10 = p0[Wimg], v11 = p0[Wimg + 1];
            const float top = fmaf(v01 - v00, dj, v00);
            const float bot = fmaf(v11 - v10, dj, v10);
            const float v = fmaf(bot - top, di, top);
            sum_in += v; sq_in = fmaf(v, v, sq_in);
        }
    }
    float sum_out = 0.f, sq_out = 0.f;
    for (int base = 0; base < n_out; base += 64) {
        const int n = base + lane;
        if (n < n_out) {
            const float sy = st_out[n * 3 + 0], sx = st_out[n * 3 + 1];
            const float ci = fmaf(A00, sy, fmaf(A01, sx, px));
            const float cj = fmaf(A10, sy, fmaf(A11, sx, py));
            const float fi = fminf(fmaxf(floorf(ci), 0.f), fImax);
            const float fj = fminf(fmaxf(floorf(cj), 0.f), fJmax);
            const float di = fminf(fmaxf(ci - fi, 0.f), 1.f);
            const float dj = fminf(fmaxf(cj - fj, 0.f), 1.f);
            const float* p0 = img + ((int)fi * Wimg + (int)fj);
            const float v00 = p0[0], v01 = p0[1], v10 = p0[Wimg], v11 = p0[Wimg + 1];
            const float top = fmaf(v01 - v00, dj, v00);
            const float bot = fmaf(v11 - v10, dj, v10);
            const float v = fmaf(bot - top, di, top);
            sum_out += v; sq_out = fmaf(v, v, sq_out);
        }
    }
    #pragma unroll
    for (int off = 32; off > 0; off >>= 1) {
        sum_in += __shfl_xor(sum_in, off);  sq_in += __shfl_xor(sq_in, off);
        sum_out += __shfl_xor(sum_out, off); sq_out += __shfl_xor(sq_out, off);
    }
    if (lane == 0) {
        const float ni = (float)n_in, no = (float)n_out;
        const float m_in = sum_in / ni, m_out = sum_out / no;
        const float v_in = (sq_in - ni * m_in * m_in) / (ni - 1.f);
        const float v_out = (sq_out - no * m_out * m_out) / (no - 1.f);
        const float contrast = (m_in - m_out) / sqrtf(v_in + v_out + 1e-8f);
        out[wave] = contrast * mask[wave];
    }
}

extern "C" void kernel_launch(void* const* d_in, const int* in_sizes, int n_in_bufs,
                              void* d_out, int out_size, void* d_ws, size_t ws_size,
                              hipStream_t stream) {
    (void)n_in_bufs; (void)d_ws; (void)ws_size; (void)out_size;
    const float* points = (const float*)d_in[0];
    const float* mask   = (const float*)d_in[1];
    const float* img    = (const float*)d_in[2];
    const float* st_in  = (const float*)d_in[3];
    const float* st_out = (const float*)d_in[4];
    float* out = (float*)d_out;

    const int n_points = in_sizes[0] / 5;
    const int n_in     = in_sizes[3] / 3;
    const int n_out    = in_sizes[4] / 3;
    const int hw       = in_sizes[2];

    if (n_in == 1024 && n_out == 124 && hw == 2048 * 2048) {
        contrast_kernel_wtile<<<n_points, 64, 0, stream>>>(points, mask, img, out, n_points);
    } else {
        int Wimg = 1;
        while ((long long)Wimg * Wimg < (long long)hw) Wimg <<= 1;
        const int Himg = hw / Wimg;
        const int blocks = (n_points + 3) / 4;
        contrast_kernel_generic<<<blocks, 256, 0, stream>>>(points, mask, img, st_in, st_out,
                                                            out, n_points, n_in, n_out, Himg, Wimg);
    }
}

// Round 11
// 121.380 us; speedup vs baseline: 1.0771x; 1.0771x over previous
//
#include <hip/hip_runtime.h>
#include <math.h>

// R11 theory: unified model over R0-R10 -- time ~= FETCH_SIZE / 1.3 TB/s
// (~1 L2-miss line-request per cycle per XCD). Explains R1/R8 nulls (FETCH
// unchanged) and R9/R10 regressions (FETCH up). Fix = L2 locality: process
// each point on the XCD owning its 256-image-row band (band key = pt[0],
// the ROW center -- R3/R4 keyed pt[1], which is the column: wrong axis).
//
// Zero-risk banding (no atomics / workspace / multi-dispatch, which killed
// R3/R4 containers): replicated-grid remap. Launch 8x waves; block g serves
// bucket g&7 (-> XCD g&7 under round-robin dispatch), wave-pid
// (g>>3)*4+wid; wave runs its point iff int(px)>>8 == bucket, else exits
// after one load (wave-uniform). Each point runs exactly once; body is the
// byte-identical R8-lean loop -> bit-identical results.
//
// Pre-committed reads: FETCH ~25MB & dur ~30 -> model confirmed. FETCH
// drops, dur ~49 -> TA-instr cap is real -> img4+banding next. FETCH
// unchanged -> blockIdx%8 is not XCD round-robin -> chunked swizzle next.

__global__ __launch_bounds__(256) void contrast_kernel_band(
    const float* __restrict__ points,   // (S*P, 5)
    const float* __restrict__ mask,     // (S*P)
    const float* __restrict__ img,      // (2048, 2048)
    float* __restrict__ out,            // (S*P)
    int n_points)
{
    constexpr float fImax = 2046.f;
    constexpr float fJmax = 2046.f;

    const int blk    = (int)blockIdx.x;
    const int bucket = blk & 7;                         // -> XCD (round-robin)
    const int wid    = (int)(threadIdx.x >> 6);
    const int lane   = (int)(threadIdx.x & 63u);
    const int pid    = (blk >> 3) * 4 + wid;
    if (pid >= n_points) return;

    const float* pt = points + (size_t)pid * 5;
    const float px = pt[0];                             // ROW center
    // band of this point's image rows; px in [0,2047] -> band in [0,7]
    const int band = min(max(((int)px) >> 8, 0), 7);
    if (band != bucket) return;                         // wave-uniform exit

    const float py = pt[1];
    const float a  = pt[2];
    const float b  = pt[3];
    const float th = pt[4];

    float sn, cs;
    sincosf(th, &sn, &cs);
    const float A00 = a * cs, A01 = -b * sn;   // i (row) coord
    const float A10 = a * sn, A11 =  b * cs;   // j (col) coord

    // interior: 1024 samples as 16 iterations of an 8x8 lane block
    const int   lr = lane >> 3;
    const int   lc = lane & 7;
    const float syb = fmaf((float)lr, 0.0625f, 0.03125f) - 1.0f;
    const float sxb = fmaf((float)lc, 0.0625f, 0.03125f) - 1.0f;

    float s0 = 0.f, q0 = 0.f, s1 = 0.f, q1 = 0.f;
    #pragma unroll 4
    for (int it = 0; it < 16; ++it) {
        const float dr = (float)(it >> 2) * 0.5f;   // exact for it in [0,16)
        const float dc = (float)(it & 3) * 0.5f;
        const float sy = syb + dr;
        const float sx = sxb + dc;
        const float ci = fmaf(A00, sy, fmaf(A01, sx, px));
        const float cj = fmaf(A10, sy, fmaf(A11, sx, py));
        const float fi = fminf(fmaxf(floorf(ci), 0.f), fImax);
        const float fj = fminf(fmaxf(floorf(cj), 0.f), fJmax);
        const float di = fminf(fmaxf(ci - fi, 0.f), 1.f);
        const float dj = fminf(fmaxf(cj - fj, 0.f), 1.f);
        const unsigned idx = ((unsigned)(int)fi << 11) + (unsigned)(int)fj;
        float2 r0, r1;
        __builtin_memcpy(&r0, &img[idx],         sizeof(float2));
        __builtin_memcpy(&r1, &img[idx + 2048u], sizeof(float2));
        const float top = fmaf(r0.y - r0.x, dj, r0.x);
        const float bot = fmaf(r1.y - r1.x, dj, r1.x);
        const float v   = fmaf(bot - top, di, top);
        if (it & 1) { s1 += v; q1 = fmaf(v, v, q1); }
        else        { s0 += v; q0 = fmaf(v, v, q0); }
    }
    float sum_in = s0 + s1;
    float sq_in  = q0 + q1;

    // ring: 124 samples, 2 iterations
    float sum_out = 0.f, sq_out = 0.f;
    #pragma unroll
    for (int base = 0; base < 124; base += 64) {
        const int n = base + lane;
        if (n < 124) {
            int row, col;
            if (n < 32)      { row = 0;                   col = n; }
            else if (n < 92) { row = 1 + ((n - 32) >> 1); col = (n & 1) * 31; }
            else             { row = 31;                  col = n - 92; }
            const float sy  = (fmaf((float)row, 0.0625f, 0.03125f) - 1.0f) * 1.0625f;
            const float sxo = (fmaf((float)col, 0.0625f, 0.03125f) - 1.0f) * 1.0625f;
            const float ci = fmaf(A00, sy, fmaf(A01, sxo, px));
            const float cj = fmaf(A10, sy, fmaf(A11, sxo, py));
            const float fi = fminf(fmaxf(floorf(ci), 0.f), fImax);
            const float fj = fminf(fmaxf(floorf(cj), 0.f), fJmax);
            const float di = fminf(fmaxf(ci - fi, 0.f), 1.f);
            const float dj = fminf(fmaxf(cj - fj, 0.f), 1.f);
            const unsigned idx = ((unsigned)(int)fi << 11) + (unsigned)(int)fj;
            float2 r0, r1;
            __builtin_memcpy(&r0, &img[idx],         sizeof(float2));
            __builtin_memcpy(&r1, &img[idx + 2048u], sizeof(float2));
            const float top = fmaf(r0.y - r0.x, dj, r0.x);
            const float bot = fmaf(r1.y - r1.x, dj, r1.x);
            const float v   = fmaf(bot - top, di, top);
            sum_out += v;
            sq_out = fmaf(v, v, sq_out);
        }
    }

    #pragma unroll
    for (int off = 32; off > 0; off >>= 1) {
        sum_in  += __shfl_xor(sum_in,  off);
        sq_in   += __shfl_xor(sq_in,   off);
        sum_out += __shfl_xor(sum_out, off);
        sq_out  += __shfl_xor(sq_out,  off);
    }

    if (lane == 0) {
        const float ni = 1024.f, no = 124.f;
        const float m_in  = sum_in  / ni;
        const float m_out = sum_out / no;
        const float v_in  = (sq_in  - ni * m_in  * m_in ) / (ni - 1.f);
        const float v_out = (sq_out - no * m_out * m_out) / (no - 1.f);
        const float contrast = (m_in - m_out) / sqrtf(v_in + v_out + 1e-8f);
        out[pid] = contrast * mask[pid];
    }
}

// ---------------- generic fallback for other sizes ----------------
__global__ __launch_bounds__(256) void contrast_kernel_generic(
    const float* __restrict__ points, const float* __restrict__ mask,
    const float* __restrict__ img, const float* __restrict__ st_in,
    const float* __restrict__ st_out, float* __restrict__ out,
    int n_points, int n_in, int n_out, int Himg, int Wimg)
{
    const int wave = (int)((blockIdx.x * (unsigned)blockDim.x + threadIdx.x) >> 6);
    const int lane = (int)(threadIdx.x & 63u);
    if (wave >= n_points) return;
    const float* pt = points + (size_t)wave * 5;
    const float px = pt[0], py = pt[1], a = pt[2], b = pt[3], th = pt[4];
    float sn, cs; sincosf(th, &sn, &cs);
    const float A00 = a * cs, A01 = -b * sn, A10 = a * sn, A11 = b * cs;
    const float fImax = (float)(Himg - 2), fJmax = (float)(Wimg - 2);
    float sum_in = 0.f, sq_in = 0.f;
    for (int base = 0; base < n_in; base += 64) {
        const int n = base + lane;
        if (n < n_in) {
            const float sy = st_in[n * 3 + 0], sx = st_in[n * 3 + 1];
            const float ci = fmaf(A00, sy, fmaf(A01, sx, px));
            const float cj = fmaf(A10, sy, fmaf(A11, sx, py));
            const float fi = fminf(fmaxf(floorf(ci), 0.f), fImax);
            const float fj = fminf(fmaxf(floorf(cj), 0.f), fJmax);
            const float di = fminf(fmaxf(ci - fi, 0.f), 1.f);
            const float dj = fminf(fmaxf(cj - fj, 0.f), 1.f);
            const float* p0 = img + ((int)fi * Wimg + (int)fj);
            const float v00 = p0[0], v01 = p0[1], v10 = p0[Wimg], v11 = p0[Wimg + 1];
            const float top = fmaf(v01 - v00, dj, v00);
            const float bot = fmaf(v11 - v10, dj, v10);
            const float v = fmaf(bot - top, di, top);
            sum_in += v; sq_in = fmaf(v, v, sq_in);
        }
    }
    float sum_out = 0.f, sq_out = 0.f;
    for (int base = 0; base < n_out; base += 64) {
        const int n = base + lane;
        if (n < n_out) {
            const float sy = st_out[n * 3 + 0], sx = st_out[n * 3 + 1];
            const float ci = fmaf(A00, sy, fmaf(A01, sx, px));
            const float cj = fmaf(A10, sy, fmaf(A11, sx, py));
            const float fi = fminf(fmaxf(floorf(ci), 0.f), fImax);
            const float fj = fminf(fmaxf(floorf(cj), 0.f), fJmax);
            const float di = fminf(fmaxf(ci - fi, 0.f), 1.f);
            const float dj = fminf(fmaxf(cj - fj, 0.f), 1.f);
            const float* p0 = img + ((int)fi * Wimg + (int)fj);
            const float v00 = p0[0], v01 = p0[1], v10 = p0[Wimg], v11 = p0[Wimg + 1];
            const float top = fmaf(v01 - v00, dj, v00);
            const float bot = fmaf(v11 - v10, dj, v10);
            const float v = fmaf(bot - top, di, top);
            sum_out += v; sq_out = fmaf(v, v, sq_out);
        }
    }
    #pragma unroll
    for (int off = 32; off > 0; off >>= 1) {
        sum_in += __shfl_xor(sum_in, off);  sq_in += __shfl_xor(sq_in, off);
        sum_out += __shfl_xor(sum_out, off); sq_out += __shfl_xor(sq_out, off);
    }
    if (lane == 0) {
        const float ni = (float)n_in, no = (float)n_out;
        const float m_in = sum_in / ni, m_out = sum_out / no;
        const float v_in = (sq_in - ni * m_in * m_in) / (ni - 1.f);
        const float v_out = (sq_out - no * m_out * m_out) / (no - 1.f);
        const float contrast = (m_in - m_out) / sqrtf(v_in + v_out + 1e-8f);
        out[wave] = contrast * mask[wave];
    }
}

extern "C" void kernel_launch(void* const* d_in, const int* in_sizes, int n_in_bufs,
                              void* d_out, int out_size, void* d_ws, size_t ws_size,
                              hipStream_t stream) {
    (void)n_in_bufs; (void)d_ws; (void)ws_size; (void)out_size;
    const float* points = (const float*)d_in[0];
    const float* mask   = (const float*)d_in[1];
    const float* img    = (const float*)d_in[2];
    const float* st_in  = (const float*)d_in[3];
    const float* st_out = (const float*)d_in[4];
    float* out = (float*)d_out;

    const int n_points = in_sizes[0] / 5;
    const int n_in     = in_sizes[3] / 3;
    const int n_out    = in_sizes[4] / 3;
    const int hw       = in_sizes[2];

    if (n_in == 1024 && n_out == 124 && hw == 2048 * 2048) {
        // replicated grid: 8 buckets x ceil(n_points/4) wave-groups
        const int groups = (n_points + 3) / 4;
        contrast_kernel_band<<<8 * groups, 256, 0, stream>>>(points, mask, img, out, n_points);
    } else {
        int Wimg = 1;
        while ((long long)Wimg * Wimg < (long long)hw) Wimg <<= 1;
        const int Himg = hw / Wimg;
        const int blocks = (n_points + 3) / 4;
        contrast_kernel_generic<<<blocks, 256, 0, stream>>>(points, mask, img, st_in, st_out,
                                                            out, n_points, n_in, n_out, Himg, Wimg);
    }
}

// Round 12
// 113.145 us; speedup vs baseline: 1.1555x; 1.0728x over previous
//
#include <hip/hip_runtime.h>
#include <math.h>

// R12 = revert to R8-lean (best verified: 49us main, 113.5us bench).
//
// Session ceiling argument (R0-R11): the kernel is bound by divergent
// vector-memory request processing (~3cy per 64B line-lookup per CU, hit
// or miss): ~640 line-requests/point x 64 points/CU x ~3cy ~= 120kcy
// ~= 50us, matching every structurally-distinct variant (49-53.5us).
// Proven invariant to: occupancy (R7/R8: 26->62->78%, null/spill), L2
// locality (R11: FETCH 62->10.7MB, null), MLP batching (R5/R6: compiler
// unbinds), lane layout (R1), LDS offload (R9/R10: LDS divergent gathers
// consume the same address-processing currency -> both ~65us).
// Only mover: request count (R2: 36->18 instrs = -16%), but its 64MB
// quad-table build (~15us) exceeds the ~8us saved. Net negative.
// -> R8-lean is the structural optimum of this approach.

__global__ __launch_bounds__(256) void contrast_kernel_lean(
    const float* __restrict__ points,   // (S*P, 5)
    const float* __restrict__ mask,     // (S*P)
    const float* __restrict__ img,      // (2048, 2048)
    float* __restrict__ out,            // (S*P)
    int n_points)
{
    constexpr float fImax = 2046.f;
    constexpr float fJmax = 2046.f;

    const int wave = (int)((blockIdx.x * (unsigned)blockDim.x + threadIdx.x) >> 6);
    const int lane = (int)(threadIdx.x & 63u);
    if (wave >= n_points) return;

    const float* pt = points + (size_t)wave * 5;
    const float px = pt[0];
    const float py = pt[1];
    const float a  = pt[2];
    const float b  = pt[3];
    const float th = pt[4];

    float sn, cs;
    sincosf(th, &sn, &cs);
    const float A00 = a * cs, A01 = -b * sn;   // i (row) coord
    const float A10 = a * sn, A11 =  b * cs;   // j (col) coord

    // interior: 1024 samples as 16 iterations of an 8x8 lane block
    const int   lr = lane >> 3;
    const int   lc = lane & 7;
    const float syb = fmaf((float)lr, 0.0625f, 0.03125f) - 1.0f;
    const float sxb = fmaf((float)lc, 0.0625f, 0.03125f) - 1.0f;

    float s0 = 0.f, q0 = 0.f, s1 = 0.f, q1 = 0.f;
    #pragma unroll 4
    for (int it = 0; it < 16; ++it) {
        const float dr = (float)(it >> 2) * 0.5f;   // exact for it in [0,16)
        const float dc = (float)(it & 3) * 0.5f;
        const float sy = syb + dr;
        const float sx = sxb + dc;
        const float ci = fmaf(A00, sy, fmaf(A01, sx, px));
        const float cj = fmaf(A10, sy, fmaf(A11, sx, py));
        const float fi = fminf(fmaxf(floorf(ci), 0.f), fImax);
        const float fj = fminf(fmaxf(floorf(cj), 0.f), fJmax);
        const float di = fminf(fmaxf(ci - fi, 0.f), 1.f);
        const float dj = fminf(fmaxf(cj - fj, 0.f), 1.f);
        // u32 element index -> SADDR-form loads (single-VGPR offsets)
        const unsigned idx = ((unsigned)(int)fi << 11) + (unsigned)(int)fj;
        float2 r0, r1;
        __builtin_memcpy(&r0, &img[idx],         sizeof(float2));
        __builtin_memcpy(&r1, &img[idx + 2048u], sizeof(float2));
        const float top = fmaf(r0.y - r0.x, dj, r0.x);
        const float bot = fmaf(r1.y - r1.x, dj, r1.x);
        const float v   = fmaf(bot - top, di, top);
        if (it & 1) { s1 += v; q1 = fmaf(v, v, q1); }
        else        { s0 += v; q0 = fmaf(v, v, q0); }
    }
    float sum_in = s0 + s1;
    float sq_in  = q0 + q1;

    // ring: 124 samples, 2 iterations
    float sum_out = 0.f, sq_out = 0.f;
    #pragma unroll
    for (int base = 0; base < 124; base += 64) {
        const int n = base + lane;
        if (n < 124) {
            int row, col;
            if (n < 32)      { row = 0;                   col = n; }
            else if (n < 92) { row = 1 + ((n - 32) >> 1); col = (n & 1) * 31; }
            else             { row = 31;                  col = n - 92; }
            const float sy  = (fmaf((float)row, 0.0625f, 0.03125f) - 1.0f) * 1.0625f;
            const float sxo = (fmaf((float)col, 0.0625f, 0.03125f) - 1.0f) * 1.0625f;
            const float ci = fmaf(A00, sy, fmaf(A01, sxo, px));
            const float cj = fmaf(A10, sy, fmaf(A11, sxo, py));
            const float fi = fminf(fmaxf(floorf(ci), 0.f), fImax);
            const float fj = fminf(fmaxf(floorf(cj), 0.f), fJmax);
            const float di = fminf(fmaxf(ci - fi, 0.f), 1.f);
            const float dj = fminf(fmaxf(cj - fj, 0.f), 1.f);
            const unsigned idx = ((unsigned)(int)fi << 11) + (unsigned)(int)fj;
            float2 r0, r1;
            __builtin_memcpy(&r0, &img[idx],         sizeof(float2));
            __builtin_memcpy(&r1, &img[idx + 2048u], sizeof(float2));
            const float top = fmaf(r0.y - r0.x, dj, r0.x);
            const float bot = fmaf(r1.y - r1.x, dj, r1.x);
            const float v   = fmaf(bot - top, di, top);
            sum_out += v;
            sq_out = fmaf(v, v, sq_out);
        }
    }

    #pragma unroll
    for (int off = 32; off > 0; off >>= 1) {
        sum_in  += __shfl_xor(sum_in,  off);
        sq_in   += __shfl_xor(sq_in,   off);
        sum_out += __shfl_xor(sum_out, off);
        sq_out  += __shfl_xor(sq_out,  off);
    }

    if (lane == 0) {
        const float ni = 1024.f, no = 124.f;
        const float m_in  = sum_in  / ni;
        const float m_out = sum_out / no;
        const float v_in  = (sq_in  - ni * m_in  * m_in ) / (ni - 1.f);
        const float v_out = (sq_out - no * m_out * m_out) / (no - 1.f);
        const float contrast = (m_in - m_out) / sqrtf(v_in + v_out + 1e-8f);
        out[wave] = contrast * mask[wave];
    }
}

// ---------------- generic fallback for other sizes ----------------
__global__ __launch_bounds__(256) void contrast_kernel_generic(
    const float* __restrict__ points, const float* __restrict__ mask,
    const float* __restrict__ img, const float* __restrict__ st_in,
    const float* __restrict__ st_out, float* __restrict__ out,
    int n_points, int n_in, int n_out, int Himg, int Wimg)
{
    const int wave = (int)((blockIdx.x * (unsigned)blockDim.x + threadIdx.x) >> 6);
    const int lane = (int)(threadIdx.x & 63u);
    if (wave >= n_points) return;
    const float* pt = points + (size_t)wave * 5;
    const float px = pt[0], py = pt[1], a = pt[2], b = pt[3], th = pt[4];
    float sn, cs; sincosf(th, &sn, &cs);
    const float A00 = a * cs, A01 = -b * sn, A10 = a * sn, A11 = b * cs;
    const float fImax = (float)(Himg - 2), fJmax = (float)(Wimg - 2);
    float sum_in = 0.f, sq_in = 0.f;
    for (int base = 0; base < n_in; base += 64) {
        const int n = base + lane;
        if (n < n_in) {
            const float sy = st_in[n * 3 + 0], sx = st_in[n * 3 + 1];
            const float ci = fmaf(A00, sy, fmaf(A01, sx, px));
            const float cj = fmaf(A10, sy, fmaf(A11, sx, py));
            const float fi = fminf(fmaxf(floorf(ci), 0.f), fImax);
            const float fj = fminf(fmaxf(floorf(cj), 0.f), fJmax);
            const float di = fminf(fmaxf(ci - fi, 0.f), 1.f);
            const float dj = fminf(fmaxf(cj - fj, 0.f), 1.f);
            const float* p0 = img + ((int)fi * Wimg + (int)fj);
            const float v00 = p0[0], v01 = p0[1], v10 = p0[Wimg], v11 = p0[Wimg + 1];
            const float top = fmaf(v01 - v00, dj, v00);
            const float bot = fmaf(v11 - v10, dj, v10);
            const float v = fmaf(bot - top, di, top);
            sum_in += v; sq_in = fmaf(v, v, sq_in);
        }
    }
    float sum_out = 0.f, sq_out = 0.f;
    for (int base = 0; base < n_out; base += 64) {
        const int n = base + lane;
        if (n < n_out) {
            const float sy = st_out[n * 3 + 0], sx = st_out[n * 3 + 1];
            const float ci = fmaf(A00, sy, fmaf(A01, sx, px));
            const float cj = fmaf(A10, sy, fmaf(A11, sx, py));
            const float fi = fminf(fmaxf(floorf(ci), 0.f), fImax);
            const float fj = fminf(fmaxf(floorf(cj), 0.f), fJmax);
            const float di = fminf(fmaxf(ci - fi, 0.f), 1.f);
            const float dj = fminf(fmaxf(cj - fj, 0.f), 1.f);
            const float* p0 = img + ((int)fi * Wimg + (int)fj);
            const float v00 = p0[0], v01 = p0[1], v10 = p0[Wimg], v11 = p0[Wimg + 1];
            const float top = fmaf(v01 - v00, dj, v00);
            const float bot = fmaf(v11 - v10, dj, v10);
            const float v = fmaf(bot - top, di, top);
            sum_out += v; sq_out = fmaf(v, v, sq_out);
        }
    }
    #pragma unroll
    for (int off = 32; off > 0; off >>= 1) {
        sum_in += __shfl_xor(sum_in, off);  sq_in += __shfl_xor(sq_in, off);
        sum_out += __shfl_xor(sum_out, off); sq_out += __shfl_xor(sq_out, off);
    }
    if (lane == 0) {
        const float ni = (float)n_in, no = (float)n_out;
        const float m_in = sum_in / ni, m_out = sum_out / no;
        const float v_in = (sq_in - ni * m_in * m_in) / (ni - 1.f);
        const float v_out = (sq_out - no * m_out * m_out) / (no - 1.f);
        const float contrast = (m_in - m_out) / sqrtf(v_in + v_out + 1e-8f);
        out[wave] = contrast * mask[wave];
    }
}

extern "C" void kernel_launch(void* const* d_in, const int* in_sizes, int n_in_bufs,
                              void* d_out, int out_size, void* d_ws, size_t ws_size,
                              hipStream_t stream) {
    (void)n_in_bufs; (void)d_ws; (void)ws_size; (void)out_size;
    const float* points = (const float*)d_in[0];
    const float* mask   = (const float*)d_in[1];
    const float* img    = (const float*)d_in[2];
    const float* st_in  = (const float*)d_in[3];
    const float* st_out = (const float*)d_in[4];
    float* out = (float*)d_out;

    const int n_points = in_sizes[0] / 5;
    const int n_in     = in_sizes[3] / 3;
    const int n_out    = in_sizes[4] / 3;
    const int hw       = in_sizes[2];

    const int waves_per_block = 4;  // 256 threads
    const int blocks = (n_points + waves_per_block - 1) / waves_per_block;

    if (n_in == 1024 && n_out == 124 && hw == 2048 * 2048) {
        contrast_kernel_lean<<<blocks, 256, 0, stream>>>(points, mask, img, out, n_points);
    } else {
        int Wimg = 1;
        while ((long long)Wimg * Wimg < (long long)hw) Wimg <<= 1;
        const int Himg = hw / Wimg;
        contrast_kernel_generic<<<blocks, 256, 0, stream>>>(points, mask, img, st_in, st_out,
                                                            out, n_points, n_in, n_out, Himg, Wimg);
    }
}